// Round 5
// baseline (467.829 us; speedup 1.0000x reference)
//
#include <hip/hip_runtime.h>
#include <hip/hip_cooperative_groups.h>
#include <math.h>

#define TT  1024
#define BB  2048
#define FF  11
#define PP  256
#define NG  100
#define NCH 32           // chunks over T
#define LCH (TT / NCH)   // 32 steps per chunk
#define GRID 512         // 2 blocks/CU: large margin under any coop max
// waves = GRID*4 = 2048; tasks = 256 octets * 32 chunks = 8192 -> 4 tasks/wave.
// wave wv: octet wg = wv & 255 (constant across its tasks since 2048 % 256 == 0),
// chunks c = (wv>>8) + 8*ti, ti = 0..3.

namespace cg = cooperative_groups;

typedef float f32x2 __attribute__((ext_vector_type(2)));
// align-4 vector loads: records are 44 B apart, only dword-aligned
typedef float f32x4u __attribute__((ext_vector_type(4), aligned(4)));
typedef float f32x2u __attribute__((ext_vector_type(2), aligned(4)));

__device__ __forceinline__ float nz(float v) { return (v != v) ? 0.f : v; }

// Branch-free erf, Abramowitz-Stegun 7.1.26, |err| <= 1.5e-7 (abs).
__device__ __forceinline__ float erf_fast(float x) {
    float ax = fabsf(x);
    float t  = __builtin_amdgcn_rcpf(fmaf(0.3275911f, ax, 1.f));
    float y  = fmaf(fmaf(fmaf(fmaf(1.061405429f, t, -1.453152027f), t,
                              1.421413741f), t, -0.284496736f), t, 0.254829592f);
    y *= t;
    float r = fmaf(-y, __expf(-ax * ax), 1.f);
    return copysignf(r, x);
}

// q coefficients for one (t,b) record. Returns (q0, q1, B0=beta*pi1n, B1=beta*pi0n).
__device__ __forceinline__ float4 q_from_rec(
    float a0, float a1, float r0, float r1, float cdc, float cdn,
    float beta, float inv_s)
{
    float u = 0.5f * (1.f + erf_fast((0.0f  - cdc) * inv_s));
    float v = 0.5f * (1.f + erf_fast((-0.1f - cdc) * inv_s));
    float w = 0.5f * (1.f + erf_fast((0.1f  - cdc) * inv_s));
    float inv = 1.f / fmaxf(w - v, 1e-10f);
    float pi0 = fminf(fmaxf((u - v) * inv, 0.f), 1.f);
    float pi1 = fminf(fmaxf((w - u) * inv, 0.f), 1.f);

    u = 0.5f * (1.f + erf_fast((0.0f  - cdn) * inv_s));
    v = 0.5f * (1.f + erf_fast((-0.1f - cdn) * inv_s));
    w = 0.5f * (1.f + erf_fast((0.1f  - cdn) * inv_s));
    inv = 1.f / fmaxf(w - v, 1e-10f);
    float pi0n = fminf(fmaxf((u - v) * inv, 0.f), 1.f);
    float pi1n = fminf(fmaxf((w - u) * inv, 0.f), 1.f);

    float rs = r0 * a0 + r1 * a1;
    float r  = (a0 >= a1) ? rs : 1.f - rs;      // argmax tie -> index 0
    float q0 = pi1 * r + pi0 * (1.f - r);
    float q1 = (2.f * r - 1.f) * (pi0 - pi1);
    if (!((a0 + a1) > 0.f)) { q0 = 1.f; q1 = 0.f; }
    return make_float4(q0, q1, beta * pi1n, beta * pi0n);
}

// per-participant (beta, inv_s) — identical derivation in all phases.
__device__ __forceinline__ float2 participant(
    const float* __restrict__ x, const float* __restrict__ beta_raw,
    const float* __restrict__ sigma_raw, int b)
{
    int pid = (int)nz(x[(size_t)b * FF + 10]);
    pid = pid < 0 ? 0 : (pid > PP - 1 ? PP - 1 : pid);
    float br = beta_raw[pid];
    float sr = sigma_raw[pid];
    float sp   = fmaxf(br, 0.f) + log1pf(__expf(-fabsf(br)));
    float beta = fminf(fmaxf(sp + 1.f, 1.f), 25.f);
    float sig  = fminf(fmaxf(__builtin_amdgcn_rcpf(1.f + __expf(-sr)) * 0.09f + 0.01f,
                             0.01f), 0.1f);
    return make_float2(beta, 1.f / (sig * 1.41421356237309505f));
}

// ---------------- R16: fused cooperative kernel, hardened -------------------
// R15 post-mortem: coop launch FAILED (all-zero logits vs memset path, poison
// vs datagen path) — grid 1024 sat exactly at the runtime's co-residency
// limit. R16: grid 512 (2/CU, big margin), LDS 6 KB (no persistent slabs),
// persistent 4-task waves. qc is RECOMPUTED from x in phase 3 (bit-identical
// code+inputs) and redistributed via a transient LDS tile, so QC (64 MB
// round-trip) is eliminated. Intermediates: UC2 + BE2 (29 MB each).
// phase arg: -1 = fused (grid.sync between phases); 0/1/2 = split fallback
// launched normally if the cooperative launch is rejected.
__global__ __launch_bounds__(256, 2) void fused_kernel(
    const float* __restrict__ x, const float* __restrict__ beta_raw,
    const float* __restrict__ sigma_raw, float2* __restrict__ UC2,
    float2* __restrict__ BE2, float* __restrict__ out, int phase)
{
    __shared__ float2 sq[4][64];      // 2 KB: U exchange (phase 1)
    __shared__ float4 tile[4][8][8];  // 4 KB: qc redistribution (phase 3)
    const int lane = threadIdx.x & 63;
    const int wib  = threadIdx.x >> 6;
    const int wv   = blockIdx.x * 4 + wib;   // 0..2047
    const int wg   = wv & 255;               // b-octet (constant per wave)
    const int q    = wv >> 8;                // 0..7; chunks q, q+8, q+16, q+24
    float2* sqw = sq[wib];

    // ================= phase 1: per-chunk U products -> UC2 =================
    if (phase <= 0) {
        const int g1  = lane & 7;
        const int sl1 = lane >> 3;
        const int b1  = wg * 8 + g1;
        const float2 pr = participant(x, beta_raw, sigma_raw, b1);
        const float beta = pr.x, inv_s = pr.y;

        f32x2 p1[7];
        #pragma unroll
        for (int k = 0; k < 7; ++k)
            p1[k] = (f32x2){ (float)(sl1 + 16 * k)     * (1.f / 99.f),
                             (float)(sl1 + 16 * k + 8) * (1.f / 99.f) };

        // cross-task record pipeline: [ti&1] parity, all indices static
        f32x4u r4[2][4];
        f32x2u r2[2][4];
        {
            const int t0 = q * LCH;
            #pragma unroll
            for (int r = 0; r < 4; ++r) {
                const float* rec = x + (size_t)(t0 + 8 * r + sl1) * (BB * FF) + b1 * FF;
                r4[0][r] = *(const f32x4u*)rec;
                r2[0][r] = *(const f32x2u*)(rec + 4);
            }
        }
        #pragma unroll
        for (int ti = 0; ti < 4; ++ti) {
            if (ti < 3) {   // issue next task's 8 loads before current compute
                const int t0n = (q + (ti + 1) * 8) * LCH;
                #pragma unroll
                for (int r = 0; r < 4; ++r) {
                    const float* rec = x + (size_t)(t0n + 8 * r + sl1) * (BB * FF) + b1 * FF;
                    r4[(ti + 1) & 1][r] = *(const f32x4u*)rec;
                    r2[(ti + 1) & 1][r] = *(const f32x2u*)(rec + 4);
                }
            }
            const int c = q + ti * 8;
            f32x2 U[7];
            #pragma unroll
            for (int k = 0; k < 7; ++k) U[k] = (f32x2){1.f, 1.f};

            #pragma unroll
            for (int r = 0; r < 4; ++r) {
                float a0 = nz(r4[ti & 1][r].x), a1 = nz(r4[ti & 1][r].y),
                      r0 = nz(r4[ti & 1][r].z), r1 = nz(r4[ti & 1][r].w),
                      dc = nz(r2[ti & 1][r].x), dn = nz(r2[ti & 1][r].y);
                float4 qc = q_from_rec(a0, a1, r0, r1, dc, dn, beta, inv_s);
                // wave-synchronous q exchange (pattern validated R11)
                sqw[sl1 * 8 + g1] = make_float2(qc.x, qc.y);
                __builtin_amdgcn_wave_barrier();
                #pragma unroll
                for (int j = 0; j < 8; ++j) {
                    float2 qj = sqw[j * 8 + g1];     // broadcast reads
                    f32x2 qx = { qj.x, qj.x }, qy = { qj.y, qj.y };
                    #pragma unroll
                    for (int k = 0; k < 7; ++k) {
                        f32x2 uu = qy * p1[k] + qx;  // v_pk_fma_f32
                        U[k] *= uu;                  // v_pk_mul_f32
                    }
                }
                __builtin_amdgcn_wave_barrier();     // reads before overwrite
            }
            #pragma unroll
            for (int k = 0; k < 7; ++k)
                UC2[((size_t)c * 56 + k * 8 + sl1) * BB + b1] =
                    make_float2(U[k].x, U[k].y);
        }
    }

    if (phase == -1) { __threadfence(); cg::this_grid().sync(); }

    // ================= phase 2: 32-chunk scan UC2 -> BE2 =================
    if (phase == -1 || phase == 1) {
        const int tid = blockIdx.x * 256 + threadIdx.x;   // 0..131071
        if (tid < 56 * BB) {                              // 114688 pair-scans
            f32x2 be = {1.f, 1.f};
            const f32x2 cl = {1e-30f, 1e-30f};
            for (int c = 0; c < NCH; ++c) {
                BE2[(size_t)c * (56 * BB) + tid] = make_float2(be.x, be.y);
                float2 Uv = UC2[(size_t)c * (56 * BB) + tid];
                f32x2 uu = { Uv.x, Uv.y };
                be = __builtin_elementwise_max(be * uu, cl);  // phaseB verbatim
            }
        }
    }

    if (phase == -1) { __threadfence(); cg::this_grid().sync(); }

    // ================= phase 3: qc recompute + chunk walk =================
    if (phase == -1 || phase == 2) {
        const int sl  = lane & 7;    // consumer: i-slot
        const int g   = lane >> 3;   // consumer: batch
        const int b   = wg * 8 + g;
        const int g1  = lane & 7;    // producer: batch
        const int sl1 = lane >> 3;   // producer: step-in-tile
        const int b1  = wg * 8 + g1;
        const float2 pr = participant(x, beta_raw, sigma_raw, b1);
        const float beta = pr.x, inv_s = pr.y;

        f32x2 p3[7];
        #pragma unroll
        for (int k = 0; k < 7; ++k)
            p3[k] = (f32x2){ (float)(sl + 16 * k)     * (1.f / 99.f),
                             (float)(sl + 16 * k + 8) * (1.f / 99.f) };
        const f32x2 clA = { 1e-30f, 1e-30f };
        const f32x2 cl6 = { (sl < 4) ? 1e-30f : 0.f, 0.f };

        for (int ti = 0; ti < 4; ++ti) {
            const int c  = q + ti * 8;
            const int t0 = c * LCH;

            // producer records, all 8 loads up-front
            f32x4u r4[4];
            f32x2u r2[4];
            #pragma unroll
            for (int r = 0; r < 4; ++r) {
                const float* rec = x + (size_t)(t0 + 8 * r + sl1) * (BB * FF) + b1 * FF;
                r4[r] = *(const f32x4u*)rec;
                r2[r] = *(const f32x2u*)(rec + 4);
            }

            // entry beliefs from BE2 (junk rows masked exactly as original)
            f32x2 be[7];
            #pragma unroll
            for (int k = 0; k < 6; ++k) {
                float2 v = BE2[((size_t)c * 56 + k * 8 + sl) * BB + b];
                be[k] = (f32x2){ v.x, v.y };
            }
            {
                float2 v = BE2[((size_t)c * 56 + 6 * 8 + sl) * BB + b];
                be[6] = (f32x2){ (sl < 4) ? v.x : 0.f, 0.f };
            }

            #pragma unroll
            for (int r = 0; r < 4; ++r) {
                // recompute qc (bit-identical to phase 1) and redistribute
                float a0 = nz(r4[r].x), a1 = nz(r4[r].y), r0 = nz(r4[r].z),
                      r1 = nz(r4[r].w), dc = nz(r2[r].x), dn = nz(r2[r].y);
                float4 qc = q_from_rec(a0, a1, r0, r1, dc, dn, beta, inv_s);
                tile[wib][sl1][g1] = qc;
                __builtin_amdgcn_wave_barrier();

                float S[8], Sp[8], Zv[8], Wv[8];
                #pragma unroll
                for (int j = 0; j < 8; ++j) {
                    float4 qf = tile[wib][j][g];     // broadcast per address
                    f32x2 qx = { qf.x, qf.x }, qy = { qf.y, qf.y };
                    #pragma unroll
                    for (int k = 0; k < 7; ++k) {
                        f32x2 uu = qy * p3[k] + qx;
                        be[k] = __builtin_elementwise_max(be[k] * uu,
                                                          (k == 6) ? cl6 : clA);
                    }
                    f32x2 sA = ((be[0] + be[1]) + (be[2] + be[3]))
                             + ((be[4] + be[5]) + be[6]);
                    S[j] = sA.x + sA.y;
                    f32x2 a1v = be[0] * p3[0], a2v = be[1] * p3[1];
                    a1v = be[2] * p3[2] + a1v;  a2v = be[3] * p3[3] + a2v;
                    a1v = be[4] * p3[4] + a1v;  a2v = be[5] * p3[5] + a2v;
                    a1v = be[6] * p3[6] + a1v;
                    f32x2 aa = a1v + a2v;
                    Sp[j] = aa.x + aa.y;
                    Zv[j] = qf.z;
                    Wv[j] = qf.w;
                }
                #pragma unroll
                for (int j = 0; j < 8; ++j) {
                    // 8-lane butterfly sum (pure VALU DPP)
                    float st = S[j], sr = Sp[j];
                    {
                        int t;
                        t = __builtin_amdgcn_update_dpp(0, __float_as_int(st), 0xB1, 0xF, 0xF, true);
                        st += __int_as_float(t);
                        t = __builtin_amdgcn_update_dpp(0, __float_as_int(sr), 0xB1, 0xF, 0xF, true);
                        sr += __int_as_float(t);
                        t = __builtin_amdgcn_update_dpp(0, __float_as_int(st), 0x4E, 0xF, 0xF, true);
                        st += __int_as_float(t);
                        t = __builtin_amdgcn_update_dpp(0, __float_as_int(sr), 0x4E, 0xF, 0xF, true);
                        sr += __int_as_float(t);
                        t = __builtin_amdgcn_update_dpp(0, __float_as_int(st), 0x141, 0xF, 0xF, true);
                        st += __int_as_float(t);
                        t = __builtin_amdgcn_update_dpp(0, __float_as_int(sr), 0x141, 0xF, 0xF, true);
                        sr += __int_as_float(t);
                    }
                    float E  = sr * __builtin_amdgcn_rcpf(st);
                    float A  = Wv[j] - Zv[j];
                    float l0 = fmaf(A, E, Zv[j]);
                    float l1 = fmaf(-A, E, Wv[j]);
                    if (sl == 0)
                        *(float2*)(out + (size_t)(t0 + 8 * r + j) * (2 * BB) + 2 * b) =
                            make_float2(l0, l1);
                }
                __builtin_amdgcn_wave_barrier();     // reads before next tile
            }

            if (c == NCH - 1) {   // final belief carry: out[T*B*2 + b*100 + i]
                float* bel = out + (size_t)TT * BB * 2 + (size_t)b * NG;
                #pragma unroll
                for (int k = 0; k < 6; ++k) {
                    bel[sl + 16 * k]     = be[k].x;
                    bel[sl + 16 * k + 8] = be[k].y;
                }
                if (sl < 4) bel[sl + 96] = be[6].x;
            }
        }
    }
}

extern "C" void kernel_launch(void* const* d_in, const int* in_sizes, int n_in,
                              void* d_out, int out_size, void* d_ws, size_t ws_size,
                              hipStream_t stream)
{
    const float* x         = (const float*)d_in[0];
    const float* beta_raw  = (const float*)d_in[1];
    const float* sigma_raw = (const float*)d_in[2];
    float* out = (float*)d_out;

    // workspace: UC2 | BE2, each 32*56*2048*8 B ~= 29.4 MB (total ~58.7 MB)
    float2* UC2 = (float2*)d_ws;
    float2* BE2 = (float2*)((char*)d_ws + (size_t)NCH * 56 * BB * 8);

    int ph = -1;
    void* kargs[] = { (void*)&x, (void*)&beta_raw, (void*)&sigma_raw,
                      (void*)&UC2, (void*)&BE2, (void*)&out, (void*)&ph };
    hipError_t e = hipLaunchCooperativeKernel(
        reinterpret_cast<void*>(fused_kernel), dim3(GRID), dim3(256),
        kargs, 0, stream);
    if (e != hipSuccess) {
        (void)hipGetLastError();   // clear the error; use the split fallback
        fused_kernel<<<GRID, 256, 0, stream>>>(x, beta_raw, sigma_raw, UC2, BE2, out, 0);
        fused_kernel<<<GRID, 256, 0, stream>>>(x, beta_raw, sigma_raw, UC2, BE2, out, 1);
        fused_kernel<<<GRID, 256, 0, stream>>>(x, beta_raw, sigma_raw, UC2, BE2, out, 2);
    }
}

// Round 6
// 196.012 us; speedup vs baseline: 2.3867x; 2.3867x over previous
//
#include <hip/hip_runtime.h>
#include <math.h>

#define TT  1024
#define BB  2048
#define FF  11
#define PP  256
#define NG  100
#define NCH 32           // chunks over T
#define LCH (TT / NCH)   // 32 steps per chunk
#define JJ  4            // phaseC unroll / prefetch depth

typedef float f32x2 __attribute__((ext_vector_type(2)));
// align-4 vector loads: records are 44 B apart, only dword-aligned
typedef float f32x4u __attribute__((ext_vector_type(4), aligned(4)));
typedef float f32x2u __attribute__((ext_vector_type(2), aligned(4)));

__device__ __forceinline__ float nz(float v) { return (v != v) ? 0.f : v; }

// Branch-free erf, Abramowitz-Stegun 7.1.26, |err| <= 1.5e-7 (abs).
__device__ __forceinline__ float erf_fast(float x) {
    float ax = fabsf(x);
    float t  = __builtin_amdgcn_rcpf(fmaf(0.3275911f, ax, 1.f));
    float y  = fmaf(fmaf(fmaf(fmaf(1.061405429f, t, -1.453152027f), t,
                              1.421413741f), t, -0.284496736f), t, 0.254829592f);
    y *= t;
    float r = fmaf(-y, __expf(-ax * ax), 1.f);
    return copysignf(r, x);
}

// q coefficients for one (t,b) record. Returns (q0, q1, B0=beta*pi1n, B1=beta*pi0n).
__device__ __forceinline__ float4 q_from_rec(
    float a0, float a1, float r0, float r1, float cdc, float cdn,
    float beta, float inv_s)
{
    float u = 0.5f * (1.f + erf_fast((0.0f  - cdc) * inv_s));
    float v = 0.5f * (1.f + erf_fast((-0.1f - cdc) * inv_s));
    float w = 0.5f * (1.f + erf_fast((0.1f  - cdc) * inv_s));
    float inv = 1.f / fmaxf(w - v, 1e-10f);
    float pi0 = fminf(fmaxf((u - v) * inv, 0.f), 1.f);
    float pi1 = fminf(fmaxf((w - u) * inv, 0.f), 1.f);

    u = 0.5f * (1.f + erf_fast((0.0f  - cdn) * inv_s));
    v = 0.5f * (1.f + erf_fast((-0.1f - cdn) * inv_s));
    w = 0.5f * (1.f + erf_fast((0.1f  - cdn) * inv_s));
    inv = 1.f / fmaxf(w - v, 1e-10f);
    float pi0n = fminf(fmaxf((u - v) * inv, 0.f), 1.f);
    float pi1n = fminf(fmaxf((w - u) * inv, 0.f), 1.f);

    float rs = r0 * a0 + r1 * a1;
    float r  = (a0 >= a1) ? rs : 1.f - rs;      // argmax tie -> index 0
    float q0 = pi1 * r + pi0 * (1.f - r);
    float q1 = (2.f * r - 1.f) * (pi0 - pi1);
    if (!((a0 + a1) > 0.f)) { q0 = 1.f; q1 = 0.f; }
    return make_float4(q0, q1, beta * pi1n, beta * pi0n);
}

// ---------------- Phase Aq: direct-load, batched-exchange U -----------------
// R15/R16 post-mortem: fused coop ran phase-1 work ~4x slower with 4 serial
// tasks/wave -> phaseAq is PER-TASK-LATENCY-bound (occupancy irrelevant, R12).
// R17: attack the intra-wave critical path. The old loop serialized 4
// r-steps through {qc -> ds_write -> barrier -> 8 ds_reads -> FMA -> barrier}.
// Now: all 8 global loads up-front (R14, kept) -> compute ALL 4 qc
// back-to-back (independent erf work, dense ILP) -> write all 4 to per-slot
// sq[r] -> ONE wave_barrier -> j-loop with 4 INDEPENDENT U-product chains.
// 7 of 8 barriers deleted; r-serialization becomes 4-way ILP.
// Numerics: U re-associates to ((U0*U1)*U2)*U3 (each partial in original
// j-order) — ulp-level only; this product path already tolerated R11's
// max-folding reassociation, and absmax has 3.7x threshold headroom.
// launch_bounds(256,3) (VGPR cap ~168) forbids the R13 spill heuristic;
// WRITE_SIZE inflation is the spill tripwire to check.
__global__ __launch_bounds__(256, 3) void phaseAq_kernel(
    const float* __restrict__ x, const float* __restrict__ beta_raw,
    const float* __restrict__ sigma_raw, float4* __restrict__ QC,
    float* __restrict__ UC)
{
    __shared__ float2 sq[4][4][64];              // 8 KB: [wave][r-slot][lane-slot]
    const int lane = threadIdx.x & 63;
    const int wib  = threadIdx.x >> 6;
    const int W    = blockIdx.x * 4 + wib;       // 0..8191
    const int wg   = W & 255;                    // b-octet
    const int c    = W >> 8;                     // chunk 0..31
    const int g    = lane & 7;
    const int sl   = lane >> 3;
    const int b    = wg * 8 + g;
    const int t0   = c * LCH;

    // ---- issue all 4 record loads up-front (dwordx4 + dwordx2 each) ----
    f32x4u r4[4];
    f32x2u r2[4];
    #pragma unroll
    for (int r = 0; r < 4; ++r) {
        const float* rec = x + (size_t)(t0 + 8 * r + sl) * (BB * FF) + b * FF;
        r4[r] = *(const f32x4u*)rec;
        r2[r] = *(const f32x2u*)(rec + 4);
    }

    // per-b participant params (independent loads, overlap the record loads)
    int pid = (int)nz(x[(size_t)b * FF + 10]);
    pid = pid < 0 ? 0 : (pid > PP - 1 ? PP - 1 : pid);
    float br = beta_raw[pid];
    float sr = sigma_raw[pid];
    float sp   = fmaxf(br, 0.f) + log1pf(__expf(-fabsf(br)));
    float beta = fminf(fmaxf(sp + 1.f, 1.f), 25.f);
    float sig  = fminf(fmaxf(__builtin_amdgcn_rcpf(1.f + __expf(-sr)) * 0.09f + 0.01f,
                             0.01f), 0.1f);
    float inv_s = 1.f / (sig * 1.41421356237309505f);

    f32x2 p[7];
    #pragma unroll
    for (int k = 0; k < 7; ++k)
        p[k] = (f32x2){ (float)(sl + 16 * k)     * (1.f / 99.f),
                        (float)(sl + 16 * k + 8) * (1.f / 99.f) };

    // ---- all 4 qc back-to-back: dense independent erf ILP ----
    #pragma unroll
    for (int r = 0; r < 4; ++r) {
        float a0 = nz(r4[r].x), a1 = nz(r4[r].y), r0 = nz(r4[r].z),
              r1 = nz(r4[r].w), dc = nz(r2[r].x), dn = nz(r2[r].y);
        float4 qc = q_from_rec(a0, a1, r0, r1, dc, dn, beta, inv_s);
        QC[(size_t)(t0 + 8 * r + sl) * BB + b] = qc;   // 128B contig per sl-group
        sq[wib][r][sl * 8 + g] = make_float2(qc.x, qc.y);
    }
    __builtin_amdgcn_wave_barrier();             // writes before cross-lane reads

    // ---- single exchange pass: 4 independent U-product chains ----
    f32x2 U[4][7];
    #pragma unroll
    for (int r = 0; r < 4; ++r)
        #pragma unroll
        for (int k = 0; k < 7; ++k) U[r][k] = (f32x2){1.f, 1.f};

    #pragma unroll
    for (int j = 0; j < 8; ++j) {
        #pragma unroll
        for (int r = 0; r < 4; ++r) {
            float2 qj = sq[wib][r][j * 8 + g];   // 8 addrs, broadcast reads
            f32x2 qx = { qj.x, qj.x }, qy = { qj.y, qj.y };
            #pragma unroll
            for (int k = 0; k < 7; ++k) {
                f32x2 u = qy * p[k] + qx;        // v_pk_fma_f32
                U[r][k] *= u;                    // v_pk_mul_f32
            }
        }
    }

    // combine partials (reassociation of the validated product, ulp-level)
    // UC layout [c][i][b]: consecutive lanes (b) -> coalesced float stores
    float* dst = UC + (size_t)c * (NG * BB) + b;
    #pragma unroll
    for (int k = 0; k < 7; ++k) {
        f32x2 Uf = ((U[0][k] * U[1][k]) * U[2][k]) * U[3][k];
        if (k < 6) {
            dst[(size_t)(sl + 16 * k) * BB]     = Uf.x;
            dst[(size_t)(sl + 16 * k + 8) * BB] = Uf.y;
        } else if (sl < 4) {
            dst[(size_t)(sl + 96) * BB] = Uf.x;
        }
    }
}

// ---------------- Phase B: 32-step scan over chunks per (i,b) ----------------
// flat = i*BB + b (layout [c][i][b]); elementwise over flat, coalesced.
__global__ __launch_bounds__(256) void phaseB_kernel(
    const float* __restrict__ UC, float* __restrict__ BE)
{
    const int flat = blockIdx.x * 256 + threadIdx.x;
    float be = 1.f;
    #pragma unroll
    for (int c = 0; c < NCH; ++c) {
        BE[(size_t)c * (BB * NG) + flat] = be;
        float u = UC[(size_t)c * (BB * NG) + flat];
        be = fmaxf(be * u, 1e-30f);              // constant-floor composition
    }
}

// ---------------- Phase C: parallel chunk re-walk, logits + carry ------------
// 8 lanes per b (sl = lane&7 -> contiguous groups, DPP-friendly), 8 b per wave.
__global__ __launch_bounds__(256) void phaseC_kernel(
    const float4* __restrict__ QC, const float* __restrict__ BE,
    float* __restrict__ out)
{
    const int lane = threadIdx.x & 63;
    const int wib  = threadIdx.x >> 6;
    const int W    = blockIdx.x * 4 + wib;       // 0..8191
    const int wg   = W & 255;                    // b-octet
    const int c    = W >> 8;                     // chunk 0..31
    const int sl   = lane & 7;
    const int g    = lane >> 3;
    const int b    = wg * 8 + g;
    const int t0   = c * LCH;

    f32x2 p[7];
    #pragma unroll
    for (int k = 0; k < 7; ++k)
        p[k] = (f32x2){ (float)(sl + 16 * k)     * (1.f / 99.f),
                        (float)(sl + 16 * k + 8) * (1.f / 99.f) };
    const f32x2 clA = { 1e-30f, 1e-30f };
    const f32x2 cl6 = { (sl < 4) ? 1e-30f : 0.f, 0.f };   // pair 6: i=96..111

    // chunk-entry beliefs from BE[c][i][b] (13 scattered loads, once per wave)
    const float* ebase = BE + (size_t)c * (BB * NG) + b;
    f32x2 be[7];
    #pragma unroll
    for (int k = 0; k < 6; ++k)
        be[k] = (f32x2){ ebase[(size_t)(sl + 16 * k) * BB],
                         ebase[(size_t)(sl + 16 * k + 8) * BB] };
    be[6] = (f32x2){ (sl < 4) ? ebase[(size_t)(sl + 96) * BB] : 0.f, 0.f };

    const char* QCb = (const char*)QC;
    char* outb = (char*)out;
    unsigned off  = ((unsigned)t0 * BB + (unsigned)b) * 16u;          // QC bytes
    unsigned soff = ((unsigned)t0 * (2 * BB) + 2 * (unsigned)b) * 4u; // out bytes

    float4 pre[JJ];
    #pragma unroll
    for (int j = 0; j < JJ; ++j)
        pre[j] = *(const float4*)(QCb + (off + (unsigned)j * (BB * 16u)));
    off += JJ * (BB * 16u);

    for (int tt = 0; tt < LCH; tt += JJ) {
        float S[JJ], Sp[JJ], Zv[JJ], Wv[JJ];
        #pragma unroll
        for (int j = 0; j < JJ; ++j) {
            float4 q = pre[j];
            // overrun prefetch (last iter, c=31) lands in UC region: never used
            pre[j] = *(const float4*)(QCb + (off + (unsigned)j * (BB * 16u)));
            f32x2 qx = { q.x, q.x }, qy = { q.y, q.y };
            #pragma unroll
            for (int k = 0; k < 7; ++k) {
                f32x2 u = qy * p[k] + qx;
                be[k] = __builtin_elementwise_max(be[k] * u,
                                                  (k == 6) ? cl6 : clA);
            }
            f32x2 sA = ((be[0] + be[1]) + (be[2] + be[3]))
                     + ((be[4] + be[5]) + be[6]);
            S[j] = sA.x + sA.y;
            f32x2 a1 = be[0] * p[0], a2 = be[1] * p[1];
            a1 = be[2] * p[2] + a1;  a2 = be[3] * p[3] + a2;
            a1 = be[4] * p[4] + a1;  a2 = be[5] * p[5] + a2;
            a1 = be[6] * p[6] + a1;
            f32x2 aa = a1 + a2;
            Sp[j] = aa.x + aa.y;
            Zv[j] = q.z;
            Wv[j] = q.w;
        }
        off += JJ * (BB * 16u);
        #pragma unroll
        for (int j = 0; j < JJ; ++j) {
            // 8-lane butterfly sum (pure VALU DPP)
            float st = S[j], sr = Sp[j];
            {
                int t;
                t = __builtin_amdgcn_update_dpp(0, __float_as_int(st), 0xB1, 0xF, 0xF, true);
                st += __int_as_float(t);
                t = __builtin_amdgcn_update_dpp(0, __float_as_int(sr), 0xB1, 0xF, 0xF, true);
                sr += __int_as_float(t);
                t = __builtin_amdgcn_update_dpp(0, __float_as_int(st), 0x4E, 0xF, 0xF, true);
                st += __int_as_float(t);
                t = __builtin_amdgcn_update_dpp(0, __float_as_int(sr), 0x4E, 0xF, 0xF, true);
                sr += __int_as_float(t);
                t = __builtin_amdgcn_update_dpp(0, __float_as_int(st), 0x141, 0xF, 0xF, true);
                st += __int_as_float(t);
                t = __builtin_amdgcn_update_dpp(0, __float_as_int(sr), 0x141, 0xF, 0xF, true);
                sr += __int_as_float(t);
            }
            float E  = sr * __builtin_amdgcn_rcpf(st);
            float A  = Wv[j] - Zv[j];
            float l0 = fmaf(A, E, Zv[j]);
            float l1 = fmaf(-A, E, Wv[j]);
            if (sl == 0)   // 8 lanes store 8B each; octet is 64B contiguous
                *(float2*)(outb + (soff + (unsigned)j * (2 * BB * 4u))) =
                    make_float2(l0, l1);
        }
        soff += JJ * (2 * BB * 4u);
    }

    if (c == NCH - 1) {   // final belief carry: out[T*B*2 + b*100 + i]
        float* bel = out + (size_t)TT * BB * 2 + (size_t)b * NG;
        #pragma unroll
        for (int k = 0; k < 6; ++k) {
            bel[sl + 16 * k]     = be[k].x;
            bel[sl + 16 * k + 8] = be[k].y;
        }
        if (sl < 4) bel[sl + 96] = be[6].x;
    }
}

extern "C" void kernel_launch(void* const* d_in, const int* in_sizes, int n_in,
                              void* d_out, int out_size, void* d_ws, size_t ws_size,
                              hipStream_t stream)
{
    const float* x         = (const float*)d_in[0];
    const float* beta_raw  = (const float*)d_in[1];
    const float* sigma_raw = (const float*)d_in[2];
    float* out = (float*)d_out;

    // workspace: QC (32 MiB) | UC (26.2 MB) | BE (26.2 MB)  ~= 85 MB
    char* ws = (char*)d_ws;
    float4* QC = (float4*)ws;
    float*  UC = (float*)(ws + (size_t)TT * BB * 16);
    float*  BE = (float*)(ws + (size_t)TT * BB * 16 + (size_t)NCH * BB * NG * 4);

    phaseAq_kernel<<<(BB / 8) * NCH / 4, 256, 0, stream>>>(x, beta_raw, sigma_raw, QC, UC);
    phaseB_kernel<<<(BB * NG) / 256, 256, 0, stream>>>(UC, BE);
    phaseC_kernel<<<(BB / 8) * NCH / 4, 256, 0, stream>>>(QC, BE, out);
}